// Round 6
// baseline (845.564 us; speedup 1.0000x reference)
//
#include <hip/hip_runtime.h>

#define NCLS 1000
#define NB 4096
#define PD 512
#define GBLK 63
#define KSTRIDE 1024

typedef __attribute__((ext_vector_type(8))) short bf16x8;
typedef __attribute__((ext_vector_type(4))) float f32x4;
typedef __attribute__((ext_vector_type(16))) float f32x16;

__device__ __forceinline__ ushort f2bf(float x) {
  union { float f; unsigned u; } c; c.f = x;
  unsigned r = c.u + 0x7FFFu + ((c.u >> 16) & 1u);
  return (ushort)(r >> 16);
}
__device__ __forceinline__ float bf2f(ushort h) {
  union { unsigned u; float f; } c; c.u = ((unsigned)h) << 16; return c.f;
}

// ---------------- zero ----------------
__global__ void zero_kernel(float* p, int n) {
  int i = blockIdx.x * 256 + threadIdx.x;
  if (i < n) p[i] = 0.f;
}

// ---------------- fused class prep ----------------
__global__ __launch_bounds__(1024) void classprep(const int* __restrict__ target,
                                                  int* __restrict__ cnt_g,
                                                  int* __restrict__ offs_g,
                                                  int* __restrict__ rank,
                                                  int* __restrict__ clss,
                                                  int* __restrict__ ibuf) {
  __shared__ int cnt_s[1024];
  __shared__ int scan_s[1024];
  int t = threadIdx.x;
  cnt_s[t] = 0;
  if (t < 256) ibuf[t] = 0;
  __syncthreads();
  int tg[4];
#pragma unroll
  for (int q = 0; q < 4; ++q) {
    tg[q] = target[t + 1024 * q];
    atomicAdd(&cnt_s[tg[q]], 1);
  }
  __syncthreads();
  int myc = cnt_s[t];
  scan_s[t] = myc;
  __syncthreads();
  for (int d = 1; d < 1024; d <<= 1) {
    int v2 = (t >= d) ? scan_s[t - d] : 0;
    __syncthreads();
    scan_s[t] += v2;
    __syncthreads();
  }
  int excl = scan_s[t] - myc;
  if (t < NCLS) { cnt_g[t] = myc; offs_g[t] = excl; }
  cnt_s[t] = excl;
  __syncthreads();
#pragma unroll
  for (int q = 0; q < 4; ++q) {
    int i = t + 1024 * q;
    int pos = atomicAdd(&cnt_s[tg[q]], 1);
    rank[i] = pos;
    clss[pos] = tg[q];
  }
}

// ---------------- f32 -> bf16 hi + lo (Dekker split) ----------------
__global__ void split_kernel(const float* __restrict__ X, ushort* __restrict__ hi,
                             ushort* __restrict__ lo, int n4) {
  int i = blockIdx.x * 256 + threadIdx.x;
  if (i >= n4) return;
  float4 v = reinterpret_cast<const float4*>(X)[i];
  float vv[4] = {v.x, v.y, v.z, v.w};
  ushort h[4], l[4];
#pragma unroll
  for (int j = 0; j < 4; ++j) {
    h[j] = f2bf(vv[j]);
    l[j] = f2bf(vv[j] - bf2f(h[j]));
  }
  ushort4 h4; h4.x = h[0]; h4.y = h[1]; h4.z = h[2]; h4.w = h[3];
  ushort4 l4; l4.x = l[0]; l4.y = l[1]; l4.z = l[2]; l4.w = l[3];
  reinterpret_cast<ushort4*>(hi)[i] = h4;
  reinterpret_cast<ushort4*>(lo)[i] = l4;
}

// ---------------- split-bf16 MFMA NT GEMM, 32x32 frags, split-K x4 waves ----------------
// 64x64 tile/block. mode 1: C = max(rn[m]+cn[n]-2*dot, 0)
__global__ __launch_bounds__(256) void gemm_split(
    const ushort* __restrict__ Ahi, const ushort* __restrict__ Alo,
    const ushort* __restrict__ Bhi, const ushort* __restrict__ Blo,
    float* __restrict__ C, int M, int N, int K,
    const float* __restrict__ rn, const float* __restrict__ cn, int mode) {
  __shared__ float red[64 * 64];
  int tid = threadIdx.x, lane = tid & 63, wv = tid >> 6;
  int m0 = blockIdx.y * 64, n0 = blockIdx.x * 64;
  int r31 = lane & 31, kg = (lane >> 5) << 3;
  int kq = K >> 2, ks = wv * kq;
  // clamp OOB rows to row 0 region: their products land only in unstored outputs
  int ra0 = min(m0 + r31, M - 1), ra1 = min(m0 + 32 + r31, M - 1);
  int rb0 = min(n0 + r31, N - 1), rb1 = min(n0 + 32 + r31, N - 1);
  const ushort* pah[2] = {Ahi + (size_t)ra0 * K + ks + kg, Ahi + (size_t)ra1 * K + ks + kg};
  const ushort* pal[2] = {Alo + (size_t)ra0 * K + ks + kg, Alo + (size_t)ra1 * K + ks + kg};
  const ushort* pbh[2] = {Bhi + (size_t)rb0 * K + ks + kg, Bhi + (size_t)rb1 * K + ks + kg};
  const ushort* pbl[2] = {Blo + (size_t)rb0 * K + ks + kg, Blo + (size_t)rb1 * K + ks + kg};
  f32x16 acc[2][2];
#pragma unroll
  for (int i = 0; i < 2; ++i)
#pragma unroll
    for (int j = 0; j < 2; ++j)
#pragma unroll
      for (int r = 0; r < 16; ++r) acc[i][j][r] = 0.f;
  for (int kb = 0; kb < kq; kb += 16) {
    bf16x8 ah[2], al[2], bh[2], bl[2];
#pragma unroll
    for (int f = 0; f < 2; ++f) {
      ah[f] = *reinterpret_cast<const bf16x8*>(pah[f] + kb);
      al[f] = *reinterpret_cast<const bf16x8*>(pal[f] + kb);
      bh[f] = *reinterpret_cast<const bf16x8*>(pbh[f] + kb);
      bl[f] = *reinterpret_cast<const bf16x8*>(pbl[f] + kb);
    }
#pragma unroll
    for (int i = 0; i < 2; ++i)
#pragma unroll
      for (int j = 0; j < 2; ++j) {
        acc[i][j] = __builtin_amdgcn_mfma_f32_32x32x16_bf16(ah[i], bh[j], acc[i][j], 0, 0, 0);
        acc[i][j] = __builtin_amdgcn_mfma_f32_32x32x16_bf16(ah[i], bl[j], acc[i][j], 0, 0, 0);
        acc[i][j] = __builtin_amdgcn_mfma_f32_32x32x16_bf16(al[i], bh[j], acc[i][j], 0, 0, 0);
      }
  }
  int rbase = 4 * (lane >> 5);
  if (wv == 0) {
#pragma unroll
    for (int i = 0; i < 2; ++i)
#pragma unroll
      for (int j = 0; j < 2; ++j)
#pragma unroll
        for (int r = 0; r < 16; ++r) {
          int row = i * 32 + (r & 3) + 8 * (r >> 2) + rbase;
          red[row * 64 + j * 32 + r31] = acc[i][j][r];
        }
  }
  __syncthreads();
  if (wv != 0) {
#pragma unroll
    for (int i = 0; i < 2; ++i)
#pragma unroll
      for (int j = 0; j < 2; ++j)
#pragma unroll
        for (int r = 0; r < 16; ++r) {
          int row = i * 32 + (r & 3) + 8 * (r >> 2) + rbase;
          atomicAdd(&red[row * 64 + j * 32 + r31], acc[i][j][r]);
        }
  }
  __syncthreads();
  int c = tid & 63, rb = (tid >> 6) * 16;
  int n = n0 + c;
  if (n < N) {
    float cnv = mode ? cn[n] : 0.f;
    for (int r = rb; r < rb + 16; ++r) {
      int m = m0 + r;
      if (m < M) {
        float val = red[r * 64 + c];
        if (mode) val = fmaxf(rn[m] + cnv - 2.f * val, 0.f);
        C[(size_t)m * N + n] = val;
      }
    }
  }
}

// ---------------- feat GEMM: 32x32 frags, 8-wave split-K, 64x128 tile, sorted bf16 out ----------------
__global__ __launch_bounds__(512) void gemm_feat(
    const float* __restrict__ A, const ushort* __restrict__ B,
    const int* __restrict__ rank, ushort* __restrict__ G, int K) {
  __shared__ float red[64 * 128];
  __shared__ int rk[64];
  int tid = threadIdx.x, lane = tid & 63, wv = tid >> 6;  // 8 waves
  int m0 = blockIdx.y * 64, n0 = blockIdx.x * 128;
  if (tid < 64) rk[tid] = rank[m0 + tid];
  int r31 = lane & 31, kg = (lane >> 5) << 3;
  int kq = K >> 3, ks = wv * kq;
  const float* pa0 = A + (size_t)(m0 + r31) * K + ks + kg;
  const float* pa1 = pa0 + (size_t)32 * K;
  const ushort* pb[4];
#pragma unroll
  for (int j = 0; j < 4; ++j)
    pb[j] = B + (size_t)(n0 + j * 32 + r31) * K + ks + kg;
  f32x16 acc[2][4];
#pragma unroll
  for (int i = 0; i < 2; ++i)
#pragma unroll
    for (int j = 0; j < 4; ++j)
#pragma unroll
      for (int r = 0; r < 16; ++r) acc[i][j][r] = 0.f;
  for (int kb = 0; kb < kq; kb += 16) {
    float4 f00 = *reinterpret_cast<const float4*>(pa0 + kb);
    float4 f01 = *reinterpret_cast<const float4*>(pa0 + kb + 4);
    float4 f10 = *reinterpret_cast<const float4*>(pa1 + kb);
    float4 f11 = *reinterpret_cast<const float4*>(pa1 + kb + 4);
    bf16x8 a0, a1;
    a0[0] = (short)f2bf(f00.x); a0[1] = (short)f2bf(f00.y); a0[2] = (short)f2bf(f00.z); a0[3] = (short)f2bf(f00.w);
    a0[4] = (short)f2bf(f01.x); a0[5] = (short)f2bf(f01.y); a0[6] = (short)f2bf(f01.z); a0[7] = (short)f2bf(f01.w);
    a1[0] = (short)f2bf(f10.x); a1[1] = (short)f2bf(f10.y); a1[2] = (short)f2bf(f10.z); a1[3] = (short)f2bf(f10.w);
    a1[4] = (short)f2bf(f11.x); a1[5] = (short)f2bf(f11.y); a1[6] = (short)f2bf(f11.z); a1[7] = (short)f2bf(f11.w);
    bf16x8 b[4];
#pragma unroll
    for (int j = 0; j < 4; ++j) b[j] = *reinterpret_cast<const bf16x8*>(pb[j] + kb);
#pragma unroll
    for (int j = 0; j < 4; ++j) {
      acc[0][j] = __builtin_amdgcn_mfma_f32_32x32x16_bf16(a0, b[j], acc[0][j], 0, 0, 0);
      acc[1][j] = __builtin_amdgcn_mfma_f32_32x32x16_bf16(a1, b[j], acc[1][j], 0, 0, 0);
    }
  }
  int rbase = 4 * (lane >> 5);
  if (wv == 0) {
#pragma unroll
    for (int i = 0; i < 2; ++i)
#pragma unroll
      for (int j = 0; j < 4; ++j)
#pragma unroll
        for (int r = 0; r < 16; ++r) {
          int row = i * 32 + (r & 3) + 8 * (r >> 2) + rbase;
          red[row * 128 + j * 32 + r31] = acc[i][j][r];
        }
  }
  __syncthreads();
  if (wv != 0) {
#pragma unroll
    for (int i = 0; i < 2; ++i)
#pragma unroll
      for (int j = 0; j < 4; ++j)
#pragma unroll
        for (int r = 0; r < 16; ++r) {
          int row = i * 32 + (r & 3) + 8 * (r >> 2) + rbase;
          atomicAdd(&red[row * 128 + j * 32 + r31], acc[i][j][r]);
        }
  }
  __syncthreads();
  int c = tid & 127, rb = (tid >> 7) * 16;
  for (int r = rb; r < rb + 16; ++r)
    G[(size_t)rk[r] * PD + n0 + c] = f2bf(red[r * 128 + c]);
}

// ---------------- row norms (f32 input) ----------------
__global__ void rownorm(const float* __restrict__ X, float* __restrict__ out, int dim) {
  int r = blockIdx.x;
  float s = 0.f;
  for (int c = threadIdx.x; c < dim; c += 256) {
    float v = X[(size_t)r * dim + c];
    s += v * v;
  }
  __shared__ float red[256];
  red[threadIdx.x] = s;
  __syncthreads();
  for (int st = 128; st > 0; st >>= 1) {
    if (threadIdx.x < st) red[threadIdx.x] += red[threadIdx.x + st];
    __syncthreads();
  }
  if (threadIdx.x == 0) out[r] = red[0];
}

// ---------------- norms of sorted bf16 rows ----------------
__global__ void norms64(const ushort* __restrict__ ftg, const ushort* __restrict__ fsg,
                        float* __restrict__ ftns, float* __restrict__ fsns) {
  int r = blockIdx.x, lane = threadIdx.x;
  bf16x8 a = *reinterpret_cast<const bf16x8*>(ftg + (size_t)r * PD + lane * 8);
  bf16x8 b = *reinterpret_cast<const bf16x8*>(fsg + (size_t)r * PD + lane * 8);
  float st = 0.f, ss = 0.f;
#pragma unroll
  for (int e = 0; e < 8; ++e) {
    float x = bf2f((ushort)a[e]); st += x * x;
    float y = bf2f((ushort)b[e]); ss += y * y;
  }
#pragma unroll
  for (int off = 32; off; off >>= 1) { st += __shfl_down(st, off); ss += __shfl_down(ss, off); }
  if (lane == 0) { ftns[r] = st; fsns[r] = ss; }
}

// ---------------- within-class pair sums ----------------
__global__ void class_pairs2(const ushort* __restrict__ ftg, const ushort* __restrict__ fsg,
                             const int* __restrict__ offs, const int* __restrict__ cnt,
                             float* __restrict__ s_tt, float* __restrict__ s_ss) {
  int k = blockIdx.x;
  int c = cnt[k];
  if (c == 0) {
    if (threadIdx.x == 0) { s_tt[k] = 0.f; s_ss[k] = 0.f; }
    return;
  }
  int base = offs[k];
  int lane = threadIdx.x & 63, wave = threadIdx.x >> 6;
  int tot = c * (c - 1);
  float sumt = 0.f, sums = 0.f;
  for (int p = wave; p < tot; p += 4) {
    int i = p / (c - 1), q = p - i * (c - 1);
    int j = q + (q >= i);
    bf16x8 ta = *reinterpret_cast<const bf16x8*>(ftg + (size_t)(base + i) * PD + lane * 8);
    bf16x8 tb = *reinterpret_cast<const bf16x8*>(ftg + (size_t)(base + j) * PD + lane * 8);
    bf16x8 sa = *reinterpret_cast<const bf16x8*>(fsg + (size_t)(base + i) * PD + lane * 8);
    bf16x8 sb = *reinterpret_cast<const bf16x8*>(fsg + (size_t)(base + j) * PD + lane * 8);
    float dt = 0.f, ds = 0.f;
#pragma unroll
    for (int e = 0; e < 8; ++e) {
      float d1 = bf2f((ushort)ta[e]) - bf2f((ushort)tb[e]); dt += d1 * d1;
      float d2 = bf2f((ushort)sa[e]) - bf2f((ushort)sb[e]); ds += d2 * d2;
    }
#pragma unroll
    for (int off = 32; off; off >>= 1) { dt += __shfl_down(dt, off); ds += __shfl_down(ds, off); }
    if (lane == 0) { sumt += __expf(-0.5f * dt); sums += __expf(-0.5f * ds); }
  }
  __shared__ float rt[4], rs[4];
  if (lane == 0) { rt[wave] = sumt; rs[wave] = sums; }
  __syncthreads();
  if (threadIdx.x == 0) {
    s_tt[k] = (float)c + rt[0] + rt[1] + rt[2] + rt[3];
    s_ss[k] = (float)c + rs[0] + rs[1] + rs[2] + rs[3];
  }
}

// ---------------- MFMA Kts (32x32 frags, split-K x4) + exp + class-binned reduction ----------------
__global__ __launch_bounds__(256) void sts_mfma(
    const ushort* __restrict__ ftg, const ushort* __restrict__ fsg,
    const int* __restrict__ clss, const float* __restrict__ ftns,
    const float* __restrict__ fsns, float* __restrict__ S) {
  __shared__ float red[64 * 64];
  __shared__ float tbl[64 * 64];
  __shared__ int lclr[64], lclc[64];
  __shared__ int rslot[64], cslot[64], rcls[64], ccls[64];
  __shared__ float rns[64], cns[64];
  __shared__ int nrs_s, ncs_s;
  int tid = threadIdx.x;
  int lane = tid & 63, wv = tid >> 6;
  // XCD-aware swizzle (4096 % 8 == 0, bijective)
  int bid = blockIdx.x;
  int swz = (bid & 7) * 512 + (bid >> 3);
  int i0 = (swz >> 6) * 64, j0 = (swz & 63) * 64;

  if (tid < 64) { lclr[tid] = clss[i0 + tid]; rns[tid] = ftns[i0 + tid]; }
  else if (tid < 128) { int t = tid - 64; lclc[t] = clss[j0 + t]; cns[t] = fsns[j0 + t]; }
  for (int t = tid; t < 64 * 64; t += 256) tbl[t] = 0.f;
  __syncthreads();
  if (tid == 0) {
    int s = 0, prev = lclr[0]; rslot[0] = 0; rcls[0] = prev;
    for (int r = 1; r < 64; ++r) {
      int cc = lclr[r];
      if (cc != prev) { ++s; rcls[s] = cc; prev = cc; }
      rslot[r] = s;
    }
    nrs_s = s + 1;
  } else if (tid == 64) {
    int s = 0, prev = lclc[0]; cslot[0] = 0; ccls[0] = prev;
    for (int r = 1; r < 64; ++r) {
      int cc = lclc[r];
      if (cc != prev) { ++s; ccls[s] = cc; prev = cc; }
      cslot[r] = s;
    }
    ncs_s = s + 1;
  }

  int r31 = lane & 31, kg = (lane >> 5) << 3;
  int ks = wv * 128;
  const ushort* pa0 = ftg + (size_t)(i0 + r31) * PD + ks + kg;
  const ushort* pa1 = pa0 + (size_t)32 * PD;
  const ushort* pb0 = fsg + (size_t)(j0 + r31) * PD + ks + kg;
  const ushort* pb1 = pb0 + (size_t)32 * PD;
  f32x16 acc[2][2];
#pragma unroll
  for (int i = 0; i < 2; ++i)
#pragma unroll
    for (int j = 0; j < 2; ++j)
#pragma unroll
      for (int r = 0; r < 16; ++r) acc[i][j][r] = 0.f;
#pragma unroll
  for (int kb = 0; kb < 128; kb += 16) {
    bf16x8 a0 = *reinterpret_cast<const bf16x8*>(pa0 + kb);
    bf16x8 a1 = *reinterpret_cast<const bf16x8*>(pa1 + kb);
    bf16x8 b0 = *reinterpret_cast<const bf16x8*>(pb0 + kb);
    bf16x8 b1 = *reinterpret_cast<const bf16x8*>(pb1 + kb);
    acc[0][0] = __builtin_amdgcn_mfma_f32_32x32x16_bf16(a0, b0, acc[0][0], 0, 0, 0);
    acc[0][1] = __builtin_amdgcn_mfma_f32_32x32x16_bf16(a0, b1, acc[0][1], 0, 0, 0);
    acc[1][0] = __builtin_amdgcn_mfma_f32_32x32x16_bf16(a1, b0, acc[1][0], 0, 0, 0);
    acc[1][1] = __builtin_amdgcn_mfma_f32_32x32x16_bf16(a1, b1, acc[1][1], 0, 0, 0);
  }
  int rbase = 4 * (lane >> 5);
  if (wv == 0) {
#pragma unroll
    for (int i = 0; i < 2; ++i)
#pragma unroll
      for (int j = 0; j < 2; ++j)
#pragma unroll
        for (int r = 0; r < 16; ++r) {
          int row = i * 32 + (r & 3) + 8 * (r >> 2) + rbase;
          red[row * 64 + j * 32 + r31] = acc[i][j][r];
        }
  }
  __syncthreads();
  if (wv != 0) {
#pragma unroll
    for (int i = 0; i < 2; ++i)
#pragma unroll
      for (int j = 0; j < 2; ++j)
#pragma unroll
        for (int r = 0; r < 16; ++r) {
          int row = i * 32 + (r & 3) + 8 * (r >> 2) + rbase;
          atomicAdd(&red[row * 64 + j * 32 + r31], acc[i][j][r]);
        }
  }
  __syncthreads();

  // epilogue: exp + class-bin, run-merged, zero-skip
  int c = tid & 63, rb = (tid >> 6) * 16;
  int cs = cslot[c];
  float cnv = cns[c];
  float run = 0.f;
  int cur = rslot[rb];
  for (int r = rb; r < rb + 16; ++r) {
    float val = red[r * 64 + c];
    float d = fmaxf(rns[r] + cnv - 2.f * val, 0.f);
    float e = __expf(-0.5f * d);
    int s = rslot[r];
    if (s != cur) {
      if (run != 0.f) atomicAdd(&tbl[cur * 64 + cs], run);
      run = 0.f; cur = s;
    }
    run += e;
  }
  if (run != 0.f) atomicAdd(&tbl[cur * 64 + cs], run);
  __syncthreads();
  int NR = nrs_s, NC = ncs_s;
  for (int t = tid; t < NR * NC; t += 256) {
    int r = t / NC, c2 = t - r * NC;
    float vs = tbl[r * 64 + c2];
    if (vs != 0.f) atomicAdd(&S[(size_t)rcls[r] * NCLS + ccls[c2]], vs);
  }
}

// ---------------- combine (64x64 tiles, coalesced Km AND KmT writes) ----------------
__global__ __launch_bounds__(256) void combine(
    float* __restrict__ C, const float* __restrict__ s_tt,
    const float* __restrict__ s_ss, const float* __restrict__ S,
    const int* __restrict__ cnt, float* __restrict__ Km, float* __restrict__ KmT) {
  __shared__ float tile[64][65];
  int tid = threadIdx.x;
  int k0 = (blockIdx.x >> 4) * 64, l0 = (blockIdx.x & 15) * 64;
  int tx = tid & 63, ty = tid >> 6;
#pragma unroll
  for (int r = 0; r < 16; ++r) {
    int k = k0 + ty * 16 + r, l = l0 + tx;
    float val = 0.f;
    if (k < NCLS && l < NCLS) {
      float cw = C[(size_t)k * NCLS + l];
      int ck = cnt[k], cl = cnt[l];
      float mmd = 0.f;
      if (ck > 0 && cl > 0) {
        float fk = (float)ck, fl = (float)cl;
        mmd = s_tt[k] / (fk * fk) + s_ss[l] / (fl * fl) - 2.f * S[(size_t)k * NCLS + l] / (fk * fl);
      }
      float c = cw - 0.1f * mmd;
      C[(size_t)k * NCLS + l] = c;
      val = __expf(-10.f * c);
    }
    Km[(size_t)k * KSTRIDE + l] = val;
    tile[ty * 16 + r][tx] = val;
  }
  __syncthreads();
#pragma unroll
  for (int r = 0; r < 16; ++r) {
    int l = l0 + ty * 16 + r, k = k0 + tx;
    KmT[(size_t)l * KSTRIDE + k] = tile[tx][ty * 16 + r];
  }
}

// ---------------- persistent Sinkhorn: K in regs, fence-free LLC protocol ----------------
__global__ __launch_bounds__(256, 1) void sinkhorn4(
    const float* __restrict__ Km, const float* __restrict__ KmT,
    const float* __restrict__ C, float* __restrict__ u, float* __restrict__ v,
    int* __restrict__ ibuf, float* __restrict__ out) {
  const int tid = threadIdx.x, bid = blockIdx.x;
  const int lane = tid & 63, wave = tid >> 6;
  const float ab = 1.f / (float)NCLS;
  const int r0 = bid * 16 + wave * 4;
  int* arr = ibuf;
  int* gen8 = ibuf + 128;
  __shared__ int any_s, bflag_s;

  float km[4][16], kt[4][16];
#pragma unroll
  for (int r = 0; r < 4; ++r) {
    const float* pm = Km + (size_t)(r0 + r) * KSTRIDE + lane;
    const float* pt = KmT + (size_t)(r0 + r) * KSTRIDE + lane;
#pragma unroll
    for (int m = 0; m < 16; ++m) { km[r][m] = pm[64 * m]; kt[r][m] = pt[64 * m]; }
  }

  if (bid == 0) {
    for (int i = tid; i < 1024; i += 256) {
      __hip_atomic_store(&u[i], (i < NCLS) ? ab : 0.f, __ATOMIC_RELAXED, __HIP_MEMORY_SCOPE_AGENT);
      __hip_atomic_store(&v[i], 0.f, __ATOMIC_RELAXED, __HIP_MEMORY_SCOPE_AGENT);
    }
    if (tid == 0) __hip_atomic_store(out, 0.f, __ATOMIC_RELAXED, __HIP_MEMORY_SCOPE_AGENT);
  }
  if (tid == 0) { any_s = 0; bflag_s = 0; }

  int ph = 0;
  auto bar = [&](int useflag) -> int {
    __syncthreads();
    ++ph;
    if (tid == 0) {
      int f = useflag ? bflag_s : 0;
      __hip_atomic_store(&arr[bid], (ph << 1) | f, __ATOMIC_RELEASE, __HIP_MEMORY_SCOPE_AGENT);
    }
    if (bid == 0) {
      int f = 0;
      if (tid < GBLK) {
        int val;
        while (((val = __hip_atomic_load(&arr[tid], __ATOMIC_RELAXED, __HIP_MEMORY_SCOPE_AGENT)) >> 1) < ph)
          __builtin_amdgcn_s_sleep(1);
        f = val & 1;
      }
      unsigned long long m = __ballot(f);
      if (tid == 0) any_s = (m != 0ull) ? 1 : 0;
      __syncthreads();
      int a = any_s;
      if (tid < 8)
        __hip_atomic_store(&gen8[tid], (ph << 1) | a, __ATOMIC_RELEASE, __HIP_MEMORY_SCOPE_AGENT);
      return a;
    } else {
      if (tid == 0) {
        int g;
        while (((g = __hip_atomic_load(&gen8[bid & 7], __ATOMIC_RELAXED, __HIP_MEMORY_SCOPE_AGENT)) >> 1) < ph)
          __builtin_amdgcn_s_sleep(1);
        any_s = g & 1;
      }
      __syncthreads();
      return any_s;
    }
  };

  bar(0);

  float up[4], ucur[4], vv[16], s[4];
#pragma unroll
  for (int r = 0; r < 4; ++r) { up[r] = ab; ucur[r] = ab; }

  for (int it = 0; it < 1000; ++it) {
    float uu[16];
#pragma unroll
    for (int m = 0; m < 16; ++m)
      uu[m] = __hip_atomic_load(&u[lane + 64 * m], __ATOMIC_RELAXED, __HIP_MEMORY_SCOPE_AGENT);
#pragma unroll
    for (int r = 0; r < 4; ++r) {
      float acc = 0.f;
#pragma unroll
      for (int m = 0; m < 16; ++m) acc += kt[r][m] * uu[m];
#pragma unroll
      for (int o = 32; o; o >>= 1) acc += __shfl_down(acc, o);
      s[r] = acc;
    }
    if (lane == 0) {
#pragma unroll
      for (int r = 0; r < 4; ++r) {
        float val = (r0 + r < NCLS) ? ab / s[r] : 0.f;
        __hip_atomic_store(&v[r0 + r], val, __ATOMIC_RELAXED, __HIP_MEMORY_SCOPE_AGENT);
      }
    }
    bar(0);

#pragma unroll
    for (int m = 0; m < 16; ++m)
      vv[m] = __hip_atomic_load(&v[lane + 64 * m], __ATOMIC_RELAXED, __HIP_MEMORY_SCOPE_AGENT);
#pragma unroll
    for (int r = 0; r < 4; ++r) {
      float acc = 0.f;
#pragma unroll
      for (int m = 0; m < 16; ++m) acc += km[r][m] * vv[m];
#pragma unroll
      for (int o = 32; o; o >>= 1) acc += __shfl_down(acc, o);
      s[r] = acc;
    }
#pragma unroll
    for (int r = 0; r < 4; ++r) {
      float sv = __shfl(s[r], 0);
      float val = (r0 + r < NCLS) ? ab / sv : 0.f;
      ucur[r] = val;
      if (lane == 0)
        __hip_atomic_store(&u[r0 + r], val, __ATOMIC_RELAXED, __HIP_MEMORY_SCOPE_AGENT);
    }
    int isC = ((it & 7) == 7);
    if (isC) {
      if (lane == 0) {
        bool nc = false;
#pragma unroll
        for (int r = 0; r < 4; ++r)
          if (r0 + r < NCLS && fabsf(ucur[r] - up[r]) > 5e-4f * ucur[r]) nc = true;
        if (nc) bflag_s = 1;
      }
#pragma unroll
      for (int r = 0; r < 4; ++r) up[r] = ucur[r];
    }
    int any = bar(isC);
    if (isC) {
      if (!any) break;
      if (tid == 0) bflag_s = 0;
    }
  }

  float part = 0.f;
#pragma unroll
  for (int r = 0; r < 4; ++r) {
    if (r0 + r < NCLS) {
      const float* cr = C + (size_t)(r0 + r) * NCLS;
      float acc = 0.f;
#pragma unroll
      for (int m = 0; m < 16; ++m)
        acc += km[r][m] * vv[m] * cr[lane + 64 * m];
#pragma unroll
      for (int o = 32; o; o >>= 1) acc += __shfl_down(acc, o);
      if (lane == 0) part += ucur[r] * acc;
    }
  }
  __shared__ float pr[4];
  if (lane == 0) pr[wave] = part;
  __syncthreads();
  if (tid == 0) atomicAdd(out, pr[0] + pr[1] + pr[2] + pr[3]);
}

// ---------------- host launch ----------------
extern "C" void kernel_launch(void* const* d_in, const int* in_sizes, int n_in,
                              void* d_out, int out_size, void* d_ws, size_t ws_size,
                              hipStream_t stream) {
  const float* feat_s = (const float*)d_in[0];  // 4096 x 1024
  const float* feat_t = (const float*)d_in[1];  // 4096 x 2048
  const float* w_s = (const float*)d_in[2];     // 1000 x 1024
  const float* w_t = (const float*)d_in[3];     // 1000 x 2048
  const float* Wt = (const float*)d_in[4];      // 512 x 2048
  const float* Ws = (const float*)d_in[5];      // 512 x 1024
  const int* target = (const int*)d_in[6];      // 4096
  float* out = (float*)d_out;

  char* base = (char*)d_ws;
  size_t off = 0;
  auto alloc = [&](size_t bytes) -> void* {
    void* p = base + off;
    off += (bytes + 255) & ~(size_t)255;
    return p;
  };
  ushort* Wthi = (ushort*)alloc((size_t)512 * 2048 * 2);
  ushort* Wtlo = (ushort*)alloc((size_t)512 * 2048 * 2);
  ushort* Wshi = (ushort*)alloc((size_t)512 * 1024 * 2);
  ushort* Wslo = (ushort*)alloc((size_t)512 * 1024 * 2);
  ushort* wthi = (ushort*)alloc((size_t)NCLS * 2048 * 2);
  ushort* wtlo = (ushort*)alloc((size_t)NCLS * 2048 * 2);
  ushort* wshi = (ushort*)alloc((size_t)NCLS * 1024 * 2);
  ushort* wslo = (ushort*)alloc((size_t)NCLS * 1024 * 2);
  float* wtp   = (float*)alloc((size_t)NCLS * PD * 4);
  float* wsp   = (float*)alloc((size_t)NCLS * PD * 4);
  ushort* wtphi = (ushort*)alloc((size_t)NCLS * PD * 2);
  ushort* wtplo = (ushort*)alloc((size_t)NCLS * PD * 2);
  ushort* wsphi = (ushort*)alloc((size_t)NCLS * PD * 2);
  ushort* wsplo = (ushort*)alloc((size_t)NCLS * PD * 2);
  float* wtn   = (float*)alloc(NCLS * 4);
  float* wsn   = (float*)alloc(NCLS * 4);
  ushort* ftg  = (ushort*)alloc((size_t)NB * PD * 2);
  ushort* fsg  = (ushort*)alloc((size_t)NB * PD * 2);
  float* ftns  = (float*)alloc(NB * 4);
  float* fsns  = (float*)alloc(NB * 4);
  int* cnt     = (int*)alloc(NCLS * 4);
  int* offs    = (int*)alloc(NCLS * 4);
  int* rank    = (int*)alloc(NB * 4);
  int* clss    = (int*)alloc(NB * 4);
  float* s_tt  = (float*)alloc(NCLS * 4);
  float* s_ss  = (float*)alloc(NCLS * 4);
  float* S     = (float*)alloc((size_t)NCLS * NCLS * 4);
  float* Cm    = (float*)alloc((size_t)NCLS * NCLS * 4);
  float* Km    = (float*)alloc((size_t)KSTRIDE * KSTRIDE * 4);
  float* KmT   = (float*)alloc((size_t)KSTRIDE * KSTRIDE * 4);
  float* u     = (float*)alloc(1024 * 4);
  float* v     = (float*)alloc(1024 * 4);
  int* ibuf    = (int*)alloc(256 * 4);

  zero_kernel<<<dim3((NCLS * NCLS + 255) / 256), 256, 0, stream>>>(S, NCLS * NCLS);
  classprep<<<dim3(1), 1024, 0, stream>>>(target, cnt, offs, rank, clss, ibuf);

  split_kernel<<<dim3(512 * 2048 / 4 / 256), 256, 0, stream>>>(Wt, Wthi, Wtlo, 512 * 2048 / 4);
  split_kernel<<<dim3(512 * 1024 / 4 / 256), 256, 0, stream>>>(Ws, Wshi, Wslo, 512 * 1024 / 4);
  split_kernel<<<dim3((NCLS * 2048 / 4 + 255) / 256), 256, 0, stream>>>(w_t, wthi, wtlo, NCLS * 2048 / 4);
  split_kernel<<<dim3((NCLS * 1024 / 4 + 255) / 256), 256, 0, stream>>>(w_s, wshi, wslo, NCLS * 1024 / 4);

  gemm_split<<<dim3(PD / 64, (NCLS + 63) / 64), 256, 0, stream>>>(wthi, wtlo, Wthi, Wtlo, wtp, NCLS, PD, 2048, nullptr, nullptr, 0);
  gemm_split<<<dim3(PD / 64, (NCLS + 63) / 64), 256, 0, stream>>>(wshi, wslo, Wshi, Wslo, wsp, NCLS, PD, 1024, nullptr, nullptr, 0);

  rownorm<<<dim3(NCLS), 256, 0, stream>>>(wtp, wtn, PD);
  rownorm<<<dim3(NCLS), 256, 0, stream>>>(wsp, wsn, PD);

  split_kernel<<<dim3((NCLS * PD / 4 + 255) / 256), 256, 0, stream>>>(wtp, wtphi, wtplo, NCLS * PD / 4);
  split_kernel<<<dim3((NCLS * PD / 4 + 255) / 256), 256, 0, stream>>>(wsp, wsphi, wsplo, NCLS * PD / 4);

  gemm_split<<<dim3((NCLS + 63) / 64, (NCLS + 63) / 64), 256, 0, stream>>>(wtphi, wtplo, wsphi, wsplo, Cm, NCLS, NCLS, PD, wtn, wsn, 1);

  gemm_feat<<<dim3(PD / 128, NB / 64), 512, 0, stream>>>(feat_t, Wthi, rank, ftg, 2048);
  gemm_feat<<<dim3(PD / 128, NB / 64), 512, 0, stream>>>(feat_s, Wshi, rank, fsg, 1024);

  norms64<<<dim3(NB), 64, 0, stream>>>(ftg, fsg, ftns, fsns);

  class_pairs2<<<dim3(NCLS), 256, 0, stream>>>(ftg, fsg, offs, cnt, s_tt, s_ss);

  sts_mfma<<<dim3(NB / 64 * NB / 64), 256, 0, stream>>>(ftg, fsg, clss, ftns, fsns, S);

  combine<<<dim3(16 * 16), 256, 0, stream>>>(Cm, s_tt, s_ss, S, cnt, Km, KmT);

  sinkhorn4<<<dim3(GBLK), 256, 0, stream>>>(Km, KmT, Cm, u, v, ibuf, out);
}

// Round 7
// 541.994 us; speedup vs baseline: 1.5601x; 1.5601x over previous
//
#include <hip/hip_runtime.h>

#define NCLS 1000
#define NB 4096
#define PD 512
#define GBLK 63
#define KSTRIDE 1024

typedef __attribute__((ext_vector_type(8))) short bf16x8;
typedef __attribute__((ext_vector_type(4))) float f32x4;
typedef __attribute__((ext_vector_type(16))) float f32x16;

__device__ __forceinline__ ushort f2bf(float x) {
  union { float f; unsigned u; } c; c.f = x;
  unsigned r = c.u + 0x7FFFu + ((c.u >> 16) & 1u);
  return (ushort)(r >> 16);
}
__device__ __forceinline__ float bf2f(ushort h) {
  union { unsigned u; float f; } c; c.u = ((unsigned)h) << 16; return c.f;
}

// ---------------- zero ----------------
__global__ void zero_kernel(float* p, int n) {
  int i = blockIdx.x * 256 + threadIdx.x;
  if (i < n) p[i] = 0.f;
}

// ---------------- fused class prep ----------------
__global__ __launch_bounds__(1024) void classprep(const int* __restrict__ target,
                                                  int* __restrict__ cnt_g,
                                                  int* __restrict__ offs_g,
                                                  int* __restrict__ rank,
                                                  int* __restrict__ clss,
                                                  int* __restrict__ ibuf) {
  __shared__ int cnt_s[1024];
  __shared__ int scan_s[1024];
  int t = threadIdx.x;
  cnt_s[t] = 0;
  if (t < 256) ibuf[t] = 0;
  __syncthreads();
  int tg[4];
#pragma unroll
  for (int q = 0; q < 4; ++q) {
    tg[q] = target[t + 1024 * q];
    atomicAdd(&cnt_s[tg[q]], 1);
  }
  __syncthreads();
  int myc = cnt_s[t];
  scan_s[t] = myc;
  __syncthreads();
  for (int d = 1; d < 1024; d <<= 1) {
    int v2 = (t >= d) ? scan_s[t - d] : 0;
    __syncthreads();
    scan_s[t] += v2;
    __syncthreads();
  }
  int excl = scan_s[t] - myc;
  if (t < NCLS) { cnt_g[t] = myc; offs_g[t] = excl; }
  cnt_s[t] = excl;
  __syncthreads();
#pragma unroll
  for (int q = 0; q < 4; ++q) {
    int i = t + 1024 * q;
    int pos = atomicAdd(&cnt_s[tg[q]], 1);
    rank[i] = pos;
    clss[pos] = tg[q];
  }
}

// ---------------- f32 -> bf16 hi + lo (Dekker split) ----------------
__global__ void split_kernel(const float* __restrict__ X, ushort* __restrict__ hi,
                             ushort* __restrict__ lo, int n4) {
  int i = blockIdx.x * 256 + threadIdx.x;
  if (i >= n4) return;
  float4 v = reinterpret_cast<const float4*>(X)[i];
  float vv[4] = {v.x, v.y, v.z, v.w};
  ushort h[4], l[4];
#pragma unroll
  for (int j = 0; j < 4; ++j) {
    h[j] = f2bf(vv[j]);
    l[j] = f2bf(vv[j] - bf2f(h[j]));
  }
  ushort4 h4; h4.x = h[0]; h4.y = h[1]; h4.z = h[2]; h4.w = h[3];
  ushort4 l4; l4.x = l[0]; l4.y = l[1]; l4.z = l[2]; l4.w = l[3];
  reinterpret_cast<ushort4*>(hi)[i] = h4;
  reinterpret_cast<ushort4*>(lo)[i] = l4;
}

// ---------------- split-bf16 MFMA NT GEMM (3 mfma per product), 16x16 frags ----------------
__global__ __launch_bounds__(256) void gemm_split(
    const ushort* __restrict__ Ahi, const ushort* __restrict__ Alo,
    const ushort* __restrict__ Bhi, const ushort* __restrict__ Blo,
    float* __restrict__ C, int M, int N, int K,
    const float* __restrict__ rn, const float* __restrict__ cn, int mode) {
  int tid = threadIdx.x;
  int lane = tid & 63, wv = tid >> 6;
  int wi = wv >> 1, wj = wv & 1;
  int m0 = blockIdx.y * 64, n0 = blockIdx.x * 64;
  int rA = m0 + wi * 32, rB = n0 + wj * 32;
  int lr = lane & 15, lk = (lane >> 4) << 3;
  bf16x8 zb = {0, 0, 0, 0, 0, 0, 0, 0};
  f32x4 z4 = {0.f, 0.f, 0.f, 0.f};
  f32x4 acc[2][2];
#pragma unroll
  for (int i = 0; i < 2; ++i)
#pragma unroll
    for (int j = 0; j < 2; ++j) acc[i][j] = z4;
  for (int kb = 0; kb < K; kb += 32) {
    bf16x8 ah[2], al[2], bh[2], bl[2];
#pragma unroll
    for (int f = 0; f < 2; ++f) {
      int ra = rA + f * 16 + lr;
      if (ra < M) {
        size_t o = (size_t)ra * K + kb + lk;
        ah[f] = *reinterpret_cast<const bf16x8*>(Ahi + o);
        al[f] = *reinterpret_cast<const bf16x8*>(Alo + o);
      } else { ah[f] = zb; al[f] = zb; }
      int rb = rB + f * 16 + lr;
      if (rb < N) {
        size_t o = (size_t)rb * K + kb + lk;
        bh[f] = *reinterpret_cast<const bf16x8*>(Bhi + o);
        bl[f] = *reinterpret_cast<const bf16x8*>(Blo + o);
      } else { bh[f] = zb; bl[f] = zb; }
    }
#pragma unroll
    for (int i = 0; i < 2; ++i)
#pragma unroll
      for (int j = 0; j < 2; ++j) {
        acc[i][j] = __builtin_amdgcn_mfma_f32_16x16x32_bf16(ah[i], bh[j], acc[i][j], 0, 0, 0);
        acc[i][j] = __builtin_amdgcn_mfma_f32_16x16x32_bf16(ah[i], bl[j], acc[i][j], 0, 0, 0);
        acc[i][j] = __builtin_amdgcn_mfma_f32_16x16x32_bf16(al[i], bh[j], acc[i][j], 0, 0, 0);
      }
  }
#pragma unroll
  for (int i = 0; i < 2; ++i)
#pragma unroll
    for (int j = 0; j < 2; ++j)
#pragma unroll
      for (int r = 0; r < 4; ++r) {
        int m = rA + i * 16 + ((lane >> 4) << 2) + r;
        int n = rB + j * 16 + lr;
        if (m < M && n < N) {
          float vv = acc[i][j][r];
          if (mode == 1) vv = fmaxf(rn[m] + cn[n] - 2.f * vv, 0.f);
          C[(size_t)m * N + n] = vv;
        }
      }
}

// ---------------- bf16 MFMA feat GEMM, f32 A converted on the fly; sorted bf16 out ----------------
__global__ __launch_bounds__(256) void gemm_feat(
    const float* __restrict__ A, const ushort* __restrict__ B,
    const int* __restrict__ rank, ushort* __restrict__ G, int K) {
  __shared__ int rk[64];
  int tid = threadIdx.x;
  int lane = tid & 63, wv = tid >> 6;
  int wi = wv >> 1, wj = wv & 1;
  int m0 = blockIdx.y * 64, n0 = blockIdx.x * 64;
  if (tid < 64) rk[tid] = rank[m0 + tid];
  int lr = lane & 15, lk = (lane >> 4) << 3;
  const float* pa0 = A + (size_t)(m0 + wi * 32 + lr) * K + lk;
  const float* pa1 = pa0 + (size_t)16 * K;
  const ushort* pb0 = B + (size_t)(n0 + wj * 32 + lr) * K + lk;
  const ushort* pb1 = pb0 + (size_t)16 * K;
  f32x4 z4 = {0.f, 0.f, 0.f, 0.f};
  f32x4 a00 = z4, a01 = z4, a10 = z4, a11 = z4;
#pragma unroll 2
  for (int kb = 0; kb < K; kb += 32) {
    float4 f00 = *reinterpret_cast<const float4*>(pa0 + kb);
    float4 f01 = *reinterpret_cast<const float4*>(pa0 + kb + 4);
    float4 f10 = *reinterpret_cast<const float4*>(pa1 + kb);
    float4 f11 = *reinterpret_cast<const float4*>(pa1 + kb + 4);
    bf16x8 a0, a1;
    a0[0] = (short)f2bf(f00.x); a0[1] = (short)f2bf(f00.y); a0[2] = (short)f2bf(f00.z); a0[3] = (short)f2bf(f00.w);
    a0[4] = (short)f2bf(f01.x); a0[5] = (short)f2bf(f01.y); a0[6] = (short)f2bf(f01.z); a0[7] = (short)f2bf(f01.w);
    a1[0] = (short)f2bf(f10.x); a1[1] = (short)f2bf(f10.y); a1[2] = (short)f2bf(f10.z); a1[3] = (short)f2bf(f10.w);
    a1[4] = (short)f2bf(f11.x); a1[5] = (short)f2bf(f11.y); a1[6] = (short)f2bf(f11.z); a1[7] = (short)f2bf(f11.w);
    bf16x8 b0 = *reinterpret_cast<const bf16x8*>(pb0 + kb);
    bf16x8 b1 = *reinterpret_cast<const bf16x8*>(pb1 + kb);
    a00 = __builtin_amdgcn_mfma_f32_16x16x32_bf16(a0, b0, a00, 0, 0, 0);
    a01 = __builtin_amdgcn_mfma_f32_16x16x32_bf16(a0, b1, a01, 0, 0, 0);
    a10 = __builtin_amdgcn_mfma_f32_16x16x32_bf16(a1, b0, a10, 0, 0, 0);
    a11 = __builtin_amdgcn_mfma_f32_16x16x32_bf16(a1, b1, a11, 0, 0, 0);
  }
  __syncthreads();
  f32x4 acc[2][2] = {{a00, a01}, {a10, a11}};
#pragma unroll
  for (int i = 0; i < 2; ++i)
#pragma unroll
    for (int j = 0; j < 2; ++j)
#pragma unroll
      for (int r = 0; r < 4; ++r) {
        int rloc = wi * 32 + i * 16 + ((lane >> 4) << 2) + r;
        int n = n0 + wj * 32 + j * 16 + lr;
        G[(size_t)rk[rloc] * PD + n] = f2bf(acc[i][j][r]);
      }
}

// ---------------- row norms (f32 input) ----------------
__global__ void rownorm(const float* __restrict__ X, float* __restrict__ out, int dim) {
  int r = blockIdx.x;
  float s = 0.f;
  for (int c = threadIdx.x; c < dim; c += 256) {
    float v = X[(size_t)r * dim + c];
    s += v * v;
  }
  __shared__ float red[256];
  red[threadIdx.x] = s;
  __syncthreads();
  for (int st = 128; st > 0; st >>= 1) {
    if (threadIdx.x < st) red[threadIdx.x] += red[threadIdx.x + st];
    __syncthreads();
  }
  if (threadIdx.x == 0) out[r] = red[0];
}

// ---------------- norms of sorted bf16 rows: full + prefix-128 ----------------
__global__ void norms64(const ushort* __restrict__ ftg, const ushort* __restrict__ fsg,
                        float* __restrict__ ftns, float* __restrict__ fsns,
                        float* __restrict__ ftns2, float* __restrict__ fsns2) {
  int r = blockIdx.x, lane = threadIdx.x;
  bf16x8 a = *reinterpret_cast<const bf16x8*>(ftg + (size_t)r * PD + lane * 8);
  bf16x8 b = *reinterpret_cast<const bf16x8*>(fsg + (size_t)r * PD + lane * 8);
  float st = 0.f, ss = 0.f;
#pragma unroll
  for (int e = 0; e < 8; ++e) {
    float x = bf2f((ushort)a[e]); st += x * x;
    float y = bf2f((ushort)b[e]); ss += y * y;
  }
  float stp = (lane < 16) ? st : 0.f;  // elems 0..127
  float ssp = (lane < 16) ? ss : 0.f;
#pragma unroll
  for (int off = 32; off; off >>= 1) {
    st += __shfl_down(st, off); ss += __shfl_down(ss, off);
    stp += __shfl_down(stp, off); ssp += __shfl_down(ssp, off);
  }
  if (lane == 0) { ftns[r] = st; fsns[r] = ss; ftns2[r] = stp; fsns2[r] = ssp; }
}

// ---------------- within-class pair sums ----------------
__global__ void class_pairs2(const ushort* __restrict__ ftg, const ushort* __restrict__ fsg,
                             const int* __restrict__ offs, const int* __restrict__ cnt,
                             float* __restrict__ s_tt, float* __restrict__ s_ss) {
  int k = blockIdx.x;
  int c = cnt[k];
  if (c == 0) {
    if (threadIdx.x == 0) { s_tt[k] = 0.f; s_ss[k] = 0.f; }
    return;
  }
  int base = offs[k];
  int lane = threadIdx.x & 63, wave = threadIdx.x >> 6;
  int tot = c * (c - 1);
  float sumt = 0.f, sums = 0.f;
  for (int p = wave; p < tot; p += 4) {
    int i = p / (c - 1), q = p - i * (c - 1);
    int j = q + (q >= i);
    bf16x8 ta = *reinterpret_cast<const bf16x8*>(ftg + (size_t)(base + i) * PD + lane * 8);
    bf16x8 tb = *reinterpret_cast<const bf16x8*>(ftg + (size_t)(base + j) * PD + lane * 8);
    bf16x8 sa = *reinterpret_cast<const bf16x8*>(fsg + (size_t)(base + i) * PD + lane * 8);
    bf16x8 sb = *reinterpret_cast<const bf16x8*>(fsg + (size_t)(base + j) * PD + lane * 8);
    float dt = 0.f, ds = 0.f;
#pragma unroll
    for (int e = 0; e < 8; ++e) {
      float d1 = bf2f((ushort)ta[e]) - bf2f((ushort)tb[e]); dt += d1 * d1;
      float d2 = bf2f((ushort)sa[e]) - bf2f((ushort)sb[e]); ds += d2 * d2;
    }
#pragma unroll
    for (int off = 32; off; off >>= 1) { dt += __shfl_down(dt, off); ds += __shfl_down(ds, off); }
    if (lane == 0) { sumt += __expf(-0.5f * dt); sums += __expf(-0.5f * ds); }
  }
  __shared__ float rt[4], rs[4];
  if (lane == 0) { rt[wave] = sumt; rs[wave] = sums; }
  __syncthreads();
  if (threadIdx.x == 0) {
    s_tt[k] = (float)c + rt[0] + rt[1] + rt[2] + rt[3];
    s_ss[k] = (float)c + rs[0] + rs[1] + rs[2] + rs[3];
  }
}

// ---------------- MFMA Kts with monotone partial-distance early-out ----------------
// 4 waves x one 32x32 (32x32x16 frags). After K=128: if all partial d^2 > 300,
// the f32 exp underflows to exactly 0 (ref too) -> skip rest of K and epilogue.
__global__ __launch_bounds__(256) void sts_mfma(
    const ushort* __restrict__ ftg, const ushort* __restrict__ fsg,
    const int* __restrict__ clss, const float* __restrict__ ftns,
    const float* __restrict__ fsns, const float* __restrict__ ftns2,
    const float* __restrict__ fsns2, float* __restrict__ S) {
  __shared__ float tbl[64 * 64];
  __shared__ int lclr[64], lclc[64];
  __shared__ int rslot[64], cslot[64], rcls[64], ccls[64];
  __shared__ float rns[64], cns[64], prns[64], pcns[64];
  __shared__ int nrs_s, ncs_s;
  int tid = threadIdx.x;
  int lane = tid & 63, wv = tid >> 6;
  int wi = wv >> 1, wj = wv & 1;
  int i0 = blockIdx.y * 64, j0 = blockIdx.x * 64;

  if (tid < 64) {
    lclr[tid] = clss[i0 + tid]; rns[tid] = ftns[i0 + tid]; prns[tid] = ftns2[i0 + tid];
  } else if (tid < 128) {
    int t = tid - 64;
    lclc[t] = clss[j0 + t]; cns[t] = fsns[j0 + t]; pcns[t] = fsns2[j0 + t];
  } else {
    for (int t = tid - 128; t < 64 * 64; t += 128) tbl[t] = 0.f;
  }
  __syncthreads();
  if (tid == 0) {
    int s = 0, prev = lclr[0]; rslot[0] = 0; rcls[0] = prev;
    for (int r = 1; r < 64; ++r) {
      int cc = lclr[r];
      if (cc != prev) { ++s; rcls[s] = cc; prev = cc; }
      rslot[r] = s;
    }
    nrs_s = s + 1;
  } else if (tid == 64) {
    int s = 0, prev = lclc[0]; cslot[0] = 0; ccls[0] = prev;
    for (int r = 1; r < 64; ++r) {
      int cc = lclc[r];
      if (cc != prev) { ++s; ccls[s] = cc; prev = cc; }
      cslot[r] = s;
    }
    ncs_s = s + 1;
  }

  int r31 = lane & 31, kg = (lane >> 5) << 3;
  const ushort* pa = ftg + (size_t)(i0 + wi * 32 + r31) * PD + kg;
  const ushort* pb = fsg + (size_t)(j0 + wj * 32 + r31) * PD + kg;
  f32x16 acc0, acc1;
#pragma unroll
  for (int r = 0; r < 16; ++r) { acc0[r] = 0.f; acc1[r] = 0.f; }
  // first 128 dims (8 K-steps, 2 interleaved accumulators)
#pragma unroll
  for (int kb = 0; kb < 128; kb += 32) {
    bf16x8 a0 = *reinterpret_cast<const bf16x8*>(pa + kb);
    bf16x8 b0 = *reinterpret_cast<const bf16x8*>(pb + kb);
    bf16x8 a1 = *reinterpret_cast<const bf16x8*>(pa + kb + 16);
    bf16x8 b1 = *reinterpret_cast<const bf16x8*>(pb + kb + 16);
    acc0 = __builtin_amdgcn_mfma_f32_32x32x16_bf16(a0, b0, acc0, 0, 0, 0);
    acc1 = __builtin_amdgcn_mfma_f32_32x32x16_bf16(a1, b1, acc1, 0, 0, 0);
  }
  // partial-distance screen (monotone lower bound on full d^2)
  int rbase = 4 * (lane >> 5);
  int cloc = wj * 32 + r31;
  float minv = 1e30f;
#pragma unroll
  for (int r = 0; r < 16; ++r) {
    int rloc = wi * 32 + rbase + (r & 3) + 8 * (r >> 2);
    float d = prns[rloc] + pcns[cloc] - 2.f * (acc0[r] + acc1[r]);
    minv = fminf(minv, d);
  }
  bool skip = __all(minv > 300.f);
  if (!skip) {
#pragma unroll
    for (int kb = 128; kb < PD; kb += 32) {
      bf16x8 a0 = *reinterpret_cast<const bf16x8*>(pa + kb);
      bf16x8 b0 = *reinterpret_cast<const bf16x8*>(pb + kb);
      bf16x8 a1 = *reinterpret_cast<const bf16x8*>(pa + kb + 16);
      bf16x8 b1 = *reinterpret_cast<const bf16x8*>(pb + kb + 16);
      acc0 = __builtin_amdgcn_mfma_f32_32x32x16_bf16(a0, b0, acc0, 0, 0, 0);
      acc1 = __builtin_amdgcn_mfma_f32_32x32x16_bf16(a1, b1, acc1, 0, 0, 0);
    }
  }
  __syncthreads();  // slots built + tbl zeroed

  if (!skip) {
    int cs = cslot[cloc];
    float cnv = cns[cloc];
    float run = 0.f;
    int cur = rslot[wi * 32 + rbase];
#pragma unroll
    for (int r = 0; r < 16; ++r) {
      int rloc = wi * 32 + rbase + (r & 3) + 8 * (r >> 2);
      float d = fmaxf(rns[rloc] + cns[cloc] - 2.f * (acc0[r] + acc1[r]), 0.f);
      float e = __expf(-0.5f * d);
      int s = rslot[rloc];
      if (s != cur) {
        if (run != 0.f) atomicAdd(&tbl[cur * 64 + cs], run);
        run = 0.f; cur = s;
      }
      run += e;
    }
    if (run != 0.f) atomicAdd(&tbl[cur * 64 + cs], run);
    (void)cnv;
  }
  __syncthreads();
  int NR = nrs_s, NC = ncs_s;
  for (int t = tid; t < NR * NC; t += 256) {
    int r = t / NC, c2 = t - r * NC;
    float vs = tbl[r * 64 + c2];
    if (vs != 0.f) atomicAdd(&S[(size_t)rcls[r] * NCLS + ccls[c2]], vs);
  }
}

// ---------------- combine (64x64 tiles, coalesced Km AND KmT writes) ----------------
__global__ __launch_bounds__(256) void combine(
    float* __restrict__ C, const float* __restrict__ s_tt,
    const float* __restrict__ s_ss, const float* __restrict__ S,
    const int* __restrict__ cnt, float* __restrict__ Km, float* __restrict__ KmT) {
  __shared__ float tile[64][65];
  int tid = threadIdx.x;
  int k0 = (blockIdx.x >> 4) * 64, l0 = (blockIdx.x & 15) * 64;
  int tx = tid & 63, ty = tid >> 6;
#pragma unroll
  for (int r = 0; r < 16; ++r) {
    int k = k0 + ty * 16 + r, l = l0 + tx;
    float val = 0.f;
    if (k < NCLS && l < NCLS) {
      float cw = C[(size_t)k * NCLS + l];
      int ck = cnt[k], cl = cnt[l];
      float mmd = 0.f;
      if (ck > 0 && cl > 0) {
        float fk = (float)ck, fl = (float)cl;
        mmd = s_tt[k] / (fk * fk) + s_ss[l] / (fl * fl) - 2.f * S[(size_t)k * NCLS + l] / (fk * fl);
      }
      float c = cw - 0.1f * mmd;
      C[(size_t)k * NCLS + l] = c;
      val = __expf(-10.f * c);
    }
    Km[(size_t)k * KSTRIDE + l] = val;
    tile[ty * 16 + r][tx] = val;
  }
  __syncthreads();
#pragma unroll
  for (int r = 0; r < 16; ++r) {
    int l = l0 + ty * 16 + r, k = k0 + tx;
    KmT[(size_t)l * KSTRIDE + k] = tile[tx][ty * 16 + r];
  }
}

// ---------------- persistent Sinkhorn: K in regs, fence-free LLC protocol ----------------
__global__ __launch_bounds__(256, 1) void sinkhorn4(
    const float* __restrict__ Km, const float* __restrict__ KmT,
    const float* __restrict__ C, float* __restrict__ u, float* __restrict__ v,
    int* __restrict__ ibuf, float* __restrict__ out) {
  const int tid = threadIdx.x, bid = blockIdx.x;
  const int lane = tid & 63, wave = tid >> 6;
  const float ab = 1.f / (float)NCLS;
  const int r0 = bid * 16 + wave * 4;
  int* arr = ibuf;
  int* gen8 = ibuf + 128;
  __shared__ int any_s, bflag_s;

  float km[4][16], kt[4][16];
#pragma unroll
  for (int r = 0; r < 4; ++r) {
    const float* pm = Km + (size_t)(r0 + r) * KSTRIDE + lane;
    const float* pt = KmT + (size_t)(r0 + r) * KSTRIDE + lane;
#pragma unroll
    for (int m = 0; m < 16; ++m) { km[r][m] = pm[64 * m]; kt[r][m] = pt[64 * m]; }
  }

  if (bid == 0) {
    for (int i = tid; i < 1024; i += 256) {
      __hip_atomic_store(&u[i], (i < NCLS) ? ab : 0.f, __ATOMIC_RELAXED, __HIP_MEMORY_SCOPE_AGENT);
      __hip_atomic_store(&v[i], 0.f, __ATOMIC_RELAXED, __HIP_MEMORY_SCOPE_AGENT);
    }
    if (tid == 0) __hip_atomic_store(out, 0.f, __ATOMIC_RELAXED, __HIP_MEMORY_SCOPE_AGENT);
  }
  if (tid == 0) { any_s = 0; bflag_s = 0; }

  int ph = 0;
  auto bar = [&](int useflag) -> int {
    __syncthreads();
    ++ph;
    if (tid == 0) {
      int f = useflag ? bflag_s : 0;
      __hip_atomic_store(&arr[bid], (ph << 1) | f, __ATOMIC_RELEASE, __HIP_MEMORY_SCOPE_AGENT);
    }
    if (bid == 0) {
      int f = 0;
      if (tid < GBLK) {
        int val;
        while (((val = __hip_atomic_load(&arr[tid], __ATOMIC_RELAXED, __HIP_MEMORY_SCOPE_AGENT)) >> 1) < ph)
          __builtin_amdgcn_s_sleep(1);
        f = val & 1;
      }
      unsigned long long m = __ballot(f);
      if (tid == 0) any_s = (m != 0ull) ? 1 : 0;
      __syncthreads();
      int a = any_s;
      if (tid < 8)
        __hip_atomic_store(&gen8[tid], (ph << 1) | a, __ATOMIC_RELEASE, __HIP_MEMORY_SCOPE_AGENT);
      return a;
    } else {
      if (tid == 0) {
        int g;
        while (((g = __hip_atomic_load(&gen8[bid & 7], __ATOMIC_RELAXED, __HIP_MEMORY_SCOPE_AGENT)) >> 1) < ph)
          __builtin_amdgcn_s_sleep(1);
        any_s = g & 1;
      }
      __syncthreads();
      return any_s;
    }
  };

  bar(0);

  float up[4], ucur[4], vv[16], s[4];
#pragma unroll
  for (int r = 0; r < 4; ++r) { up[r] = ab; ucur[r] = ab; }

  for (int it = 0; it < 1000; ++it) {
    float uu[16];
#pragma unroll
    for (int m = 0; m < 16; ++m)
      uu[m] = __hip_atomic_load(&u[lane + 64 * m], __ATOMIC_RELAXED, __HIP_MEMORY_SCOPE_AGENT);
#pragma unroll
    for (int r = 0; r < 4; ++r) {
      float acc = 0.f;
#pragma unroll
      for (int m = 0; m < 16; ++m) acc += kt[r][m] * uu[m];
#pragma unroll
      for (int o = 32; o; o >>= 1) acc += __shfl_down(acc, o);
      s[r] = acc;
    }
    if (lane == 0) {
#pragma unroll
      for (int r = 0; r < 4; ++r) {
        float val = (r0 + r < NCLS) ? ab / s[r] : 0.f;
        __hip_atomic_store(&v[r0 + r], val, __ATOMIC_RELAXED, __HIP_MEMORY_SCOPE_AGENT);
      }
    }
    bar(0);

#pragma unroll
    for (int m = 0; m < 16; ++m)
      vv[m] = __hip_atomic_load(&v[lane + 64 * m], __ATOMIC_RELAXED, __HIP_MEMORY_SCOPE_AGENT);
#pragma unroll
    for (int r = 0; r < 4; ++r) {
      float acc = 0.f;
#pragma unroll
      for (int m = 0; m < 16; ++m) acc += km[r][m] * vv[m];
#pragma unroll
      for (int o = 32; o; o >>= 1) acc += __shfl_down(acc, o);
      s[r] = acc;
    }
#pragma unroll
    for (int r = 0; r < 4; ++r) {
      float sv = __shfl(s[r], 0);
      float val = (r0 + r < NCLS) ? ab / sv : 0.f;
      ucur[r] = val;
      if (lane == 0)
        __hip_atomic_store(&u[r0 + r], val, __ATOMIC_RELAXED, __HIP_MEMORY_SCOPE_AGENT);
    }
    int isC = ((it & 7) == 7);
    if (isC) {
      if (lane == 0) {
        bool nc = false;
#pragma unroll
        for (int r = 0; r < 4; ++r)
          if (r0 + r < NCLS && fabsf(ucur[r] - up[r]) > 5e-4f * ucur[r]) nc = true;
        if (nc) bflag_s = 1;
      }
#pragma unroll
      for (int r = 0; r < 4; ++r) up[r] = ucur[r];
    }
    int any = bar(isC);
    if (isC) {
      if (!any) break;
      if (tid == 0) bflag_s = 0;
    }
  }

  float part = 0.f;
#pragma unroll
  for (int r = 0; r < 4; ++r) {
    if (r0 + r < NCLS) {
      const float* cr = C + (size_t)(r0 + r) * NCLS;
      float acc = 0.f;
#pragma unroll
      for (int m = 0; m < 16; ++m)
        acc += km[r][m] * vv[m] * cr[lane + 64 * m];
#pragma unroll
      for (int o = 32; o; o >>= 1) acc += __shfl_down(acc, o);
      if (lane == 0) part += ucur[r] * acc;
    }
  }
  __shared__ float pr[4];
  if (lane == 0) pr[wave] = part;
  __syncthreads();
  if (tid == 0) atomicAdd(out, pr[0] + pr[1] + pr[2] + pr[3]);
}

// ---------------- host launch ----------------
extern "C" void kernel_launch(void* const* d_in, const int* in_sizes, int n_in,
                              void* d_out, int out_size, void* d_ws, size_t ws_size,
                              hipStream_t stream) {
  const float* feat_s = (const float*)d_in[0];  // 4096 x 1024
  const float* feat_t = (const float*)d_in[1];  // 4096 x 2048
  const float* w_s = (const float*)d_in[2];     // 1000 x 1024
  const float* w_t = (const float*)d_in[3];     // 1000 x 2048
  const float* Wt = (const float*)d_in[4];      // 512 x 2048
  const float* Ws = (const float*)d_in[5];      // 512 x 1024
  const int* target = (const int*)d_in[6];      // 4096
  float* out = (float*)d_out;

  char* base = (char*)d_ws;
  size_t off = 0;
  auto alloc = [&](size_t bytes) -> void* {
    void* p = base + off;
    off += (bytes + 255) & ~(size_t)255;
    return p;
  };
  ushort* Wthi = (ushort*)alloc((size_t)512 * 2048 * 2);
  ushort* Wtlo = (ushort*)alloc((size_t)512 * 2048 * 2);
  ushort* Wshi = (ushort*)alloc((size_t)512 * 1024 * 2);
  ushort* Wslo = (ushort*)alloc((size_t)512 * 1024 * 2);
  ushort* wthi = (ushort*)alloc((size_t)NCLS * 2048 * 2);
  ushort* wtlo = (ushort*)alloc((size_t)NCLS * 2048 * 2);
  ushort* wshi = (ushort*)alloc((size_t)NCLS * 1024 * 2);
  ushort* wslo = (ushort*)alloc((size_t)NCLS * 1024 * 2);
  float* wtp   = (float*)alloc((size_t)NCLS * PD * 4);
  float* wsp   = (float*)alloc((size_t)NCLS * PD * 4);
  ushort* wtphi = (ushort*)alloc((size_t)NCLS * PD * 2);
  ushort* wtplo = (ushort*)alloc((size_t)NCLS * PD * 2);
  ushort* wsphi = (ushort*)alloc((size_t)NCLS * PD * 2);
  ushort* wsplo = (ushort*)alloc((size_t)NCLS * PD * 2);
  float* wtn   = (float*)alloc(NCLS * 4);
  float* wsn   = (float*)alloc(NCLS * 4);
  ushort* ftg  = (ushort*)alloc((size_t)NB * PD * 2);
  ushort* fsg  = (ushort*)alloc((size_t)NB * PD * 2);
  float* ftns  = (float*)alloc(NB * 4);
  float* fsns  = (float*)alloc(NB * 4);
  float* ftns2 = (float*)alloc(NB * 4);
  float* fsns2 = (float*)alloc(NB * 4);
  int* cnt     = (int*)alloc(NCLS * 4);
  int* offs    = (int*)alloc(NCLS * 4);
  int* rank    = (int*)alloc(NB * 4);
  int* clss    = (int*)alloc(NB * 4);
  float* s_tt  = (float*)alloc(NCLS * 4);
  float* s_ss  = (float*)alloc(NCLS * 4);
  float* S     = (float*)alloc((size_t)NCLS * NCLS * 4);
  float* Cm    = (float*)alloc((size_t)NCLS * NCLS * 4);
  float* Km    = (float*)alloc((size_t)KSTRIDE * KSTRIDE * 4);
  float* KmT   = (float*)alloc((size_t)KSTRIDE * KSTRIDE * 4);
  float* u     = (float*)alloc(1024 * 4);
  float* v     = (float*)alloc(1024 * 4);
  int* ibuf    = (int*)alloc(256 * 4);

  zero_kernel<<<dim3((NCLS * NCLS + 255) / 256), 256, 0, stream>>>(S, NCLS * NCLS);
  classprep<<<dim3(1), 1024, 0, stream>>>(target, cnt, offs, rank, clss, ibuf);

  split_kernel<<<dim3(512 * 2048 / 4 / 256), 256, 0, stream>>>(Wt, Wthi, Wtlo, 512 * 2048 / 4);
  split_kernel<<<dim3(512 * 1024 / 4 / 256), 256, 0, stream>>>(Ws, Wshi, Wslo, 512 * 1024 / 4);
  split_kernel<<<dim3((NCLS * 2048 / 4 + 255) / 256), 256, 0, stream>>>(w_t, wthi, wtlo, NCLS * 2048 / 4);
  split_kernel<<<dim3((NCLS * 1024 / 4 + 255) / 256), 256, 0, stream>>>(w_s, wshi, wslo, NCLS * 1024 / 4);

  gemm_split<<<dim3(PD / 64, (NCLS + 63) / 64), 256, 0, stream>>>(wthi, wtlo, Wthi, Wtlo, wtp, NCLS, PD, 2048, nullptr, nullptr, 0);
  gemm_split<<<dim3(PD / 64, (NCLS + 63) / 64), 256, 0, stream>>>(wshi, wslo, Wshi, Wslo, wsp, NCLS, PD, 1024, nullptr, nullptr, 0);

  rownorm<<<dim3(NCLS), 256, 0, stream>>>(wtp, wtn, PD);
  rownorm<<<dim3(NCLS), 256, 0, stream>>>(wsp, wsn, PD);

  split_kernel<<<dim3((NCLS * PD / 4 + 255) / 256), 256, 0, stream>>>(wtp, wtphi, wtplo, NCLS * PD / 4);
  split_kernel<<<dim3((NCLS * PD / 4 + 255) / 256), 256, 0, stream>>>(wsp, wsphi, wsplo, NCLS * PD / 4);

  gemm_split<<<dim3((NCLS + 63) / 64, (NCLS + 63) / 64), 256, 0, stream>>>(wtphi, wtplo, wsphi, wsplo, Cm, NCLS, NCLS, PD, wtn, wsn, 1);

  gemm_feat<<<dim3(PD / 64, NB / 64), 256, 0, stream>>>(feat_t, Wthi, rank, ftg, 2048);
  gemm_feat<<<dim3(PD / 64, NB / 64), 256, 0, stream>>>(feat_s, Wshi, rank, fsg, 1024);

  norms64<<<dim3(NB), 64, 0, stream>>>(ftg, fsg, ftns, fsns, ftns2, fsns2);

  class_pairs2<<<dim3(NCLS), 256, 0, stream>>>(ftg, fsg, offs, cnt, s_tt, s_ss);

  sts_mfma<<<dim3(NB / 64, NB / 64), 256, 0, stream>>>(ftg, fsg, clss, ftns, fsns, ftns2, fsns2, S);

  combine<<<dim3(16 * 16), 256, 0, stream>>>(Cm, s_tt, s_ss, S, cnt, Km, KmT);

  sinkhorn4<<<dim3(GBLK), 256, 0, stream>>>(Km, KmT, Cm, u, v, ibuf, out);
}